// Round 1
// baseline (176.130 us; speedup 1.0000x reference)
//
#include <hip/hip_runtime.h>

// Problem constants (match reference)
#define Bb   32
#define Nn   65536
#define Dd   16
#define Hh   64
#define Mm   32
#define OUTn 3

#define CHUNKS 32   // blocks per batch for phase 1
#define TPB    256
#define NPT    2    // nodes per thread per iteration

// ---------------------------------------------------------------------------
// Prep: transpose mw1 [D][H] -> w1t [H][D] so each h-row is 16 contiguous
// floats (one s_load_dwordx16 per h in the hot loop).
__global__ void k_prep(const float* __restrict__ mw1, float* __restrict__ w1t) {
    int i = blockIdx.x * blockDim.x + threadIdx.x;  // 0..1023
    if (i < Dd * Hh) {
        int h = i / Dd, d = i % Dd;
        w1t[i] = mw1[d * Hh + h];
    }
}

// ---------------------------------------------------------------------------
// Phase 1: Hsum[b][h] = sum_n relu(x_n . W1[:,h] + b1[h])  (partials per block)
// Also stashes x_last compactly for phase 2.
__global__ __launch_bounds__(TPB) void k_mphase(
    const float* __restrict__ in, const float* __restrict__ w1t,
    const float* __restrict__ mb1, float* __restrict__ partials,
    float* __restrict__ xlast, int save_xlast)
{
    const int b     = blockIdx.x / CHUNKS;
    const int chunk = blockIdx.x % CHUNKS;
    const int npb   = Nn / CHUNKS;                       // 2048 nodes per block
    const size_t nbase = (size_t)b * Nn + (size_t)chunk * npb;
    const float* inb = in + nbase * Dd;

    float hsum[Hh];
#pragma unroll
    for (int h = 0; h < Hh; ++h) hsum[h] = 0.f;

    for (int it = 0; it < npb / (TPB * NPT); ++it) {     // 4 iterations
        const int n0 = it * TPB * NPT + threadIdx.x;     // block-local node A
        const int n1 = n0 + TPB;                         // block-local node B

        float xa[Dd], xb[Dd];
        const float4* pa = (const float4*)(inb + (size_t)n0 * Dd);
        const float4* pb = (const float4*)(inb + (size_t)n1 * Dd);
#pragma unroll
        for (int q = 0; q < 4; ++q) {
            float4 va = pa[q];
            xa[4*q+0] = va.x; xa[4*q+1] = va.y; xa[4*q+2] = va.z; xa[4*q+3] = va.w;
            float4 vb = pb[q];
            xb[4*q+0] = vb.x; xb[4*q+1] = vb.y; xb[4*q+2] = vb.z; xb[4*q+3] = vb.w;
        }
        if (save_xlast) {
            xlast[nbase + n0] = xa[Dd - 1];
            xlast[nbase + n1] = xb[Dd - 1];
        }

#pragma unroll 8
        for (int h = 0; h < Hh; ++h) {
            const float* wr = w1t + h * Dd;              // uniform -> s_load
            float t0 = mb1[h];
            float t1 = t0;
#pragma unroll
            for (int d = 0; d < Dd; ++d) {
                t0 = fmaf(xa[d], wr[d], t0);
                t1 = fmaf(xb[d], wr[d], t1);
            }
            hsum[h] += fmaxf(t0, 0.f) + fmaxf(t1, 0.f);
        }
    }

    // --- block reduction -------------------------------------------------
    // intra-wave butterfly (all 64 lanes end with the wave sum)
#pragma unroll
    for (int h = 0; h < Hh; ++h) {
        float v = hsum[h];
#pragma unroll
        for (int off = 32; off >= 1; off >>= 1) v += __shfl_xor(v, off, 64);
        hsum[h] = v;
    }
    const int lane = threadIdx.x & 63;
    const int wave = threadIdx.x >> 6;
    float mine = 0.f;
#pragma unroll
    for (int h = 0; h < Hh; ++h) mine = (lane == h) ? hsum[h] : mine;

    __shared__ float wsum[TPB / 64][Hh];
    wsum[wave][lane] = mine;
    __syncthreads();
    if (threadIdx.x < Hh) {
        float s = wsum[0][threadIdx.x] + wsum[1][threadIdx.x] +
                  wsum[2][threadIdx.x] + wsum[3][threadIdx.x];
        partials[((size_t)b * CHUNKS + chunk) * Hh + threadIdx.x] = s;
    }
}

// ---------------------------------------------------------------------------
// Combine: Hsum -> msg_sum -> base[b][h] = msg_sum . iw1[:M,h] + ib1[h]
// One block per batch, 64 threads.
__global__ void k_combine(const float* __restrict__ partials,
                          const float* __restrict__ mw2, const float* __restrict__ mb2,
                          const float* __restrict__ iw1, const float* __restrict__ ib1,
                          float* __restrict__ base)
{
    const int b = blockIdx.x;
    const int t = threadIdx.x;          // 0..63
    float hs = 0.f;
    for (int c = 0; c < CHUNKS; ++c) hs += partials[((size_t)b * CHUNKS + c) * Hh + t];
    __shared__ float Hs[Hh];
    __shared__ float ms[Mm];
    Hs[t] = hs;
    __syncthreads();
    if (t < Mm) {
        float s = (float)Nn * mb2[t];
        for (int h = 0; h < Hh; ++h) s = fmaf(Hs[h], mw2[h * Mm + t], s);
        ms[t] = s;
    }
    __syncthreads();
    float bs = ib1[t];
    for (int m = 0; m < Mm; ++m) bs = fmaf(ms[m], iw1[m * Hh + t], bs);
    base[(size_t)b * Hh + t] = bs;
}

// ---------------------------------------------------------------------------
// Phase 2: out = relu(base + x_last * iw1[M]) . iw2 + ib2  per node.
__global__ __launch_bounds__(TPB) void k_iphase(
    const float* __restrict__ xsrc, int xstride,   // compact (1) or strided in (Dd)
    const float* __restrict__ base,
    const float* __restrict__ iw1, const float* __restrict__ iw2,
    const float* __restrict__ ib2, float* __restrict__ out)
{
    const size_t blk0 = (size_t)blockIdx.x * TPB;
    const int b = (int)(blk0 / Nn);                 // uniform per block -> SGPR
    const size_t idx = blk0 + threadIdx.x;

    const float x = xsrc[idx * xstride + (xstride - 1)];
    const float* bb  = base + (size_t)b * Hh;
    const float* w1l = iw1 + (size_t)Mm * Hh;       // last row of iw1

    float o0 = ib2[0], o1 = ib2[1], o2 = ib2[2];
#pragma unroll 16
    for (int h = 0; h < Hh; ++h) {
        float g = fmaxf(fmaf(x, w1l[h], bb[h]), 0.f);
        o0 = fmaf(g, iw2[h * OUTn + 0], o0);
        o1 = fmaf(g, iw2[h * OUTn + 1], o1);
        o2 = fmaf(g, iw2[h * OUTn + 2], o2);
    }
    out[idx * 3 + 0] = o0;
    out[idx * 3 + 1] = o1;
    out[idx * 3 + 2] = o2;
}

// ---------------------------------------------------------------------------
extern "C" void kernel_launch(void* const* d_in, const int* in_sizes, int n_in,
                              void* d_out, int out_size, void* d_ws, size_t ws_size,
                              hipStream_t stream) {
    const float* in  = (const float*)d_in[0];
    const float* mw1 = (const float*)d_in[1];
    const float* mb1 = (const float*)d_in[2];
    const float* mw2 = (const float*)d_in[3];
    const float* mb2 = (const float*)d_in[4];
    const float* iw1 = (const float*)d_in[5];
    const float* ib1 = (const float*)d_in[6];
    const float* iw2 = (const float*)d_in[7];
    const float* ib2 = (const float*)d_in[8];
    float* out = (float*)d_out;

    char* ws = (char*)d_ws;
    float* w1t      = (float*)(ws);                          // 4 KiB
    float* partials = (float*)(ws + 4096);                   // 256 KiB
    float* base     = (float*)(ws + 4096 + 262144);          // 8 KiB
    float* xlast    = (float*)(ws + 4096 + 262144 + 8192);   // 8 MiB
    const size_t need = 4096 + 262144 + 8192 + (size_t)Bb * Nn * sizeof(float);
    const int use_xlast = (ws_size >= need) ? 1 : 0;

    hipLaunchKernelGGL(k_prep, dim3(4), dim3(256), 0, stream, mw1, w1t);
    hipLaunchKernelGGL(k_mphase, dim3(Bb * CHUNKS), dim3(TPB), 0, stream,
                       in, w1t, mb1, partials, xlast, use_xlast);
    hipLaunchKernelGGL(k_combine, dim3(Bb), dim3(Hh), 0, stream,
                       partials, mw2, mb2, iw1, ib1, base);
    hipLaunchKernelGGL(k_iphase, dim3((Bb * Nn) / TPB), dim3(TPB), 0, stream,
                       use_xlast ? xlast : in, use_xlast ? 1 : Dd,
                       base, iw1, iw2, ib2, out);
}

// Round 2
// 150.716 us; speedup vs baseline: 1.1686x; 1.1686x over previous
//
#include <hip/hip_runtime.h>

// Problem constants (match reference)
#define Bb   32
#define Nn   65536
#define Dd   16
#define Hh   64
#define Mm   32
#define OUTn 3

#define NPW   256              // nodes processed per wave in mphase
#define WPB_N (Nn / NPW)       // mphase waves per batch = 256
#define TPB   256

// ---------------------------------------------------------------------------
// Prep: transpose mw1 [D][H] -> w1t [H][D] so lane h loads 16 contiguous floats.
__global__ void k_prep(const float* __restrict__ mw1, float* __restrict__ w1t) {
    int i = blockIdx.x * blockDim.x + threadIdx.x;
    if (i < Dd * Hh) {
        int h = i / Dd, d = i % Dd;
        w1t[i] = mw1[d * Hh + h];
    }
}

// ---------------------------------------------------------------------------
// Phase 1, lane = h layout:
//   lane h keeps W1[:,h] (16 floats) + bias in VGPRs for the whole kernel.
//   Node features are wave-uniform -> scalar loads -> v_fmac with 1 SGPR src.
//   acc (per lane) = partial Hsum[b][h] over this wave's 256 nodes.
__global__ __launch_bounds__(TPB) void k_mphase(
    const float* __restrict__ in, const float* __restrict__ w1t,
    const float* __restrict__ mb1, float* __restrict__ partials,
    float* __restrict__ xlast)
{
    const int lane = threadIdx.x & 63;
    const int wid  = __builtin_amdgcn_readfirstlane(
                         blockIdx.x * (TPB / 64) + (threadIdx.x >> 6)); // 0..8191
    const size_t node0 = (size_t)wid * NPW;

    // per-lane weights: lane = h
    float wv[Dd];
    const float4* wp = (const float4*)(w1t + lane * Dd);
#pragma unroll
    for (int q = 0; q < 4; ++q) {
        float4 v = wp[q];
        wv[4*q+0] = v.x; wv[4*q+1] = v.y; wv[4*q+2] = v.z; wv[4*q+3] = v.w;
    }
    const float bias = mb1[lane];
    float acc = 0.f;

    const float* __restrict__ xp = in + node0 * Dd;   // wave-uniform base

    for (int g = 0; g < NPW / 64; ++g) {              // 4 groups of 64 nodes
#pragma unroll 4
        for (int i = 0; i < 64; ++i) {
            const float* __restrict__ xn = xp + (size_t)(g * 64 + i) * Dd; // uniform
            float t = bias;
#pragma unroll
            for (int d = 0; d < Dd; ++d)
                t = fmaf(xn[d], wv[d], t);            // v_fmac vdst, s_x, v_w
            acc += fmaxf(t, 0.f);
        }
        // xlast for this group's 64 nodes: stride-64B gather (L2-hot) + coalesced store
        xlast[node0 + (size_t)g * 64 + lane] =
            xp[(size_t)(g * 64 + lane) * Dd + (Dd - 1)];
    }

    partials[(size_t)wid * Hh + lane] = acc;          // lane=h, coalesced
}

// ---------------------------------------------------------------------------
// Combine: Hsum -> msg_sum -> base[b][h] = msg_sum . iw1[:M,h] + ib1[h]
// One block per batch, 64 threads.
__global__ void k_combine(const float* __restrict__ partials,
                          const float* __restrict__ mw2, const float* __restrict__ mb2,
                          const float* __restrict__ iw1, const float* __restrict__ ib1,
                          float* __restrict__ base)
{
    const int b = blockIdx.x;
    const int t = threadIdx.x;          // 0..63
    float hs = 0.f;
    for (int c = 0; c < WPB_N; ++c)
        hs += partials[((size_t)b * WPB_N + c) * Hh + t];
    __shared__ float Hs[Hh];
    __shared__ float ms[Mm];
    Hs[t] = hs;
    __syncthreads();
    if (t < Mm) {
        float s = (float)Nn * mb2[t];
        for (int h = 0; h < Hh; ++h) s = fmaf(Hs[h], mw2[h * Mm + t], s);
        ms[t] = s;
    }
    __syncthreads();
    float bs = ib1[t];
    for (int m = 0; m < Mm; ++m) bs = fmaf(ms[m], iw1[m * Hh + t], bs);
    base[(size_t)b * Hh + t] = bs;
}

// ---------------------------------------------------------------------------
// Phase 2: out = relu(base + x_last * iw1[M]) . iw2 + ib2  per node.
__global__ __launch_bounds__(TPB) void k_iphase(
    const float* __restrict__ xsrc, int xstride,   // compact (1) or strided in (Dd)
    const float* __restrict__ base,
    const float* __restrict__ iw1, const float* __restrict__ iw2,
    const float* __restrict__ ib2, float* __restrict__ out)
{
    const size_t blk0 = (size_t)blockIdx.x * TPB;
    const int b = (int)(blk0 / Nn);                 // uniform per block
    const size_t idx = blk0 + threadIdx.x;

    const float x = xsrc[idx * xstride + (xstride - 1)];
    const float* bb  = base + (size_t)b * Hh;
    const float* w1l = iw1 + (size_t)Mm * Hh;       // last row of iw1

    float o0 = ib2[0], o1 = ib2[1], o2 = ib2[2];
#pragma unroll 16
    for (int h = 0; h < Hh; ++h) {
        float g = fmaxf(fmaf(x, w1l[h], bb[h]), 0.f);
        o0 = fmaf(g, iw2[h * OUTn + 0], o0);
        o1 = fmaf(g, iw2[h * OUTn + 1], o1);
        o2 = fmaf(g, iw2[h * OUTn + 2], o2);
    }
    out[idx * 3 + 0] = o0;
    out[idx * 3 + 1] = o1;
    out[idx * 3 + 2] = o2;
}

// ---------------------------------------------------------------------------
extern "C" void kernel_launch(void* const* d_in, const int* in_sizes, int n_in,
                              void* d_out, int out_size, void* d_ws, size_t ws_size,
                              hipStream_t stream) {
    const float* in  = (const float*)d_in[0];
    const float* mw1 = (const float*)d_in[1];
    const float* mb1 = (const float*)d_in[2];
    const float* mw2 = (const float*)d_in[3];
    const float* mb2 = (const float*)d_in[4];
    const float* iw1 = (const float*)d_in[5];
    const float* ib1 = (const float*)d_in[6];
    const float* iw2 = (const float*)d_in[7];
    const float* ib2 = (const float*)d_in[8];
    float* out = (float*)d_out;

    char* ws = (char*)d_ws;
    const size_t PART_SZ = (size_t)Bb * WPB_N * Hh * sizeof(float);  // 2 MiB
    float* w1t      = (float*)(ws);                                   // 4 KiB
    float* partials = (float*)(ws + 4096);
    float* base     = (float*)(ws + 4096 + PART_SZ);                  // 8 KiB
    float* xlast    = (float*)(ws + 4096 + PART_SZ + 8192);           // 8 MiB
    const size_t need = 4096 + PART_SZ + 8192 + (size_t)Bb * Nn * sizeof(float);
    const int use_xlast = (ws_size >= need) ? 1 : 0;

    const int nwaves  = (Bb * Nn) / NPW;          // 8192
    const int nblocks = nwaves / (TPB / 64);      // 2048

    hipLaunchKernelGGL(k_prep, dim3(4), dim3(256), 0, stream, mw1, w1t);
    hipLaunchKernelGGL(k_mphase, dim3(nblocks), dim3(TPB), 0, stream,
                       in, w1t, mb1, partials, xlast);
    hipLaunchKernelGGL(k_combine, dim3(Bb), dim3(Hh), 0, stream,
                       partials, mw2, mb2, iw1, ib1, base);
    hipLaunchKernelGGL(k_iphase, dim3((Bb * Nn) / TPB), dim3(TPB), 0, stream,
                       use_xlast ? xlast : in, use_xlast ? 1 : Dd,
                       base, iw1, iw2, ib2, out);
}

// Round 3
// 59.532 us; speedup vs baseline: 2.9586x; 2.5317x over previous
//
#include <hip/hip_runtime.h>

// Problem constants (match reference)
#define Bb   32
#define Nn   65536
#define Dd   16
#define Hh   64
#define Mm   32
#define OUTn 3

#define NPW   256              // nodes per wave in mphase
#define WPB_N (Nn / NPW)       // mphase waves per batch = 256
#define TPB   256

typedef __attribute__((ext_vector_type(8)))  __bf16 bf16x8;
typedef __attribute__((ext_vector_type(16))) float  f32x16;
typedef __attribute__((ext_vector_type(4)))  float  f32x4;

static __device__ inline void split_bf(float w, __bf16& hi, __bf16& lo) {
    hi = (__bf16)w;                 // RNE hardware cvt
    lo = (__bf16)(w - (float)hi);   // residual, |err| <= 2^-16 |w|
}

// ---------------------------------------------------------------------------
// Phase 1 via MFMA: per 32-node tile, D[node][h] = x.W1 + b, relu, sum rows.
//   A[32x16] = node features (bf16), B[16x32] = W1 half (bf16 hi+lo chained),
//   C-init = bias[col]. Node axis is fully reduced, so A/D row mappings are
//   irrelevant; D col = lane&31 (verified layout) labels h.
__global__ __launch_bounds__(TPB) void k_mphase(
    const float* __restrict__ in, const float* __restrict__ mw1,
    const float* __restrict__ mb1, float* __restrict__ partials,
    float* __restrict__ xlast)
{
    const int lane = threadIdx.x & 63;
    const int l31  = lane & 31;
    const int half = lane >> 5;                        // k-part: feats 8*half..
    const int wid  = blockIdx.x * (TPB / 64) + (threadIdx.x >> 6);
    const size_t node0 = (size_t)wid * NPW;

    // B fragments: B[k][col], k = 8*half + e. Half A: h = l31; half B: h = 32+l31.
    bf16x8 bhiA, bloA, bhiB, bloB;
#pragma unroll
    for (int e = 0; e < 8; ++e) {
        const int k = 8 * half + e;
        __bf16 h, l;
        split_bf(mw1[k * Hh + l31], h, l);        bhiA[e] = h; bloA[e] = l;
        split_bf(mw1[k * Hh + 32 + l31], h, l);   bhiB[e] = h; bloB[e] = l;
    }
    const float biasA = mb1[l31];
    const float biasB = mb1[32 + l31];

    float hsumA = 0.f, hsumB = 0.f;
    const float* __restrict__ inw = in + node0 * Dd;

    for (int s = 0; s < NPW / 32; ++s) {               // 8 tiles of 32 nodes
        // lane: row = l31, k-slice = 8*half..8*half+7  (32B contiguous/lane)
        const float* ap = inw + ((size_t)(s * 32 + l31)) * Dd + 8 * half;
        f32x4 v0 = *(const f32x4*)ap;
        f32x4 v1 = *(const f32x4*)(ap + 4);
        bf16x8 a;
        a[0] = (__bf16)v0[0]; a[1] = (__bf16)v0[1];
        a[2] = (__bf16)v0[2]; a[3] = (__bf16)v0[3];
        a[4] = (__bf16)v1[0]; a[5] = (__bf16)v1[1];
        a[6] = (__bf16)v1[2]; a[7] = (__bf16)v1[3];

        f32x16 accA, accB;
#pragma unroll
        for (int r = 0; r < 16; ++r) { accA[r] = biasA; accB[r] = biasB; }
        accA = __builtin_amdgcn_mfma_f32_32x32x16_bf16(a, bloA, accA, 0, 0, 0);
        accA = __builtin_amdgcn_mfma_f32_32x32x16_bf16(a, bhiA, accA, 0, 0, 0);
        accB = __builtin_amdgcn_mfma_f32_32x32x16_bf16(a, bloB, accB, 0, 0, 0);
        accB = __builtin_amdgcn_mfma_f32_32x32x16_bf16(a, bhiB, accB, 0, 0, 0);

        // relu + tree-sum over the 16 rows this lane holds
        float mA[16], mB[16];
#pragma unroll
        for (int r = 0; r < 16; ++r) {
            mA[r] = fmaxf(accA[r], 0.f);
            mB[r] = fmaxf(accB[r], 0.f);
        }
#pragma unroll
        for (int st = 8; st >= 1; st >>= 1)
#pragma unroll
            for (int r = 0; r < st; ++r) { mA[r] += mA[r + st]; mB[r] += mB[r + st]; }
        hsumA += mA[0]; hsumB += mB[0];

        // stash x_last: lanes>=32 hold feat 15 of node (s*32 + l31) in v1.w
        float x15 = __shfl_xor(v1[3], 32, 64);
        if (lane < 32) xlast[node0 + (size_t)s * 32 + lane] = x15;
    }

    // combine the two half-wave row groups -> full column sums
    hsumA += __shfl_xor(hsumA, 32, 64);
    hsumB += __shfl_xor(hsumB, 32, 64);
    partials[(size_t)wid * Hh + lane] = (lane < 32) ? hsumA : hsumB;
}

// ---------------------------------------------------------------------------
// Combine: Hsum -> msg_sum -> base[b][h] = msg_sum . iw1[:M,h] + ib1[h]
__global__ void k_combine(const float* __restrict__ partials,
                          const float* __restrict__ mw2, const float* __restrict__ mb2,
                          const float* __restrict__ iw1, const float* __restrict__ ib1,
                          float* __restrict__ base)
{
    const int b = blockIdx.x;
    const int t = threadIdx.x;          // 0..63
    float hs = 0.f;
    for (int c = 0; c < WPB_N; ++c)
        hs += partials[((size_t)b * WPB_N + c) * Hh + t];
    __shared__ float Hs[Hh];
    __shared__ float ms[Mm];
    Hs[t] = hs;
    __syncthreads();
    if (t < Mm) {
        float s = (float)Nn * mb2[t];
        for (int h = 0; h < Hh; ++h) s = fmaf(Hs[h], mw2[h * Mm + t], s);
        ms[t] = s;
    }
    __syncthreads();
    float bs = ib1[t];
    for (int m = 0; m < Mm; ++m) bs = fmaf(ms[m], iw1[m * Hh + t], bs);
    base[(size_t)b * Hh + t] = bs;
}

// ---------------------------------------------------------------------------
// Phase 2: out = relu(base + x_last * iw1[M]) . iw2 + ib2  per node.
__global__ __launch_bounds__(TPB) void k_iphase(
    const float* __restrict__ xsrc, int xstride,
    const float* __restrict__ base,
    const float* __restrict__ iw1, const float* __restrict__ iw2,
    const float* __restrict__ ib2, float* __restrict__ out)
{
    const size_t blk0 = (size_t)blockIdx.x * TPB;
    const int b = (int)(blk0 / Nn);                 // uniform per block
    const size_t idx = blk0 + threadIdx.x;

    const float x = xsrc[idx * xstride + (xstride - 1)];
    const float* bb  = base + (size_t)b * Hh;
    const float* w1l = iw1 + (size_t)Mm * Hh;       // last row of iw1

    float o0 = ib2[0], o1 = ib2[1], o2 = ib2[2];
#pragma unroll 16
    for (int h = 0; h < Hh; ++h) {
        float g = fmaxf(fmaf(x, w1l[h], bb[h]), 0.f);
        o0 = fmaf(g, iw2[h * OUTn + 0], o0);
        o1 = fmaf(g, iw2[h * OUTn + 1], o1);
        o2 = fmaf(g, iw2[h * OUTn + 2], o2);
    }
    out[idx * 3 + 0] = o0;
    out[idx * 3 + 1] = o1;
    out[idx * 3 + 2] = o2;
}

// ---------------------------------------------------------------------------
extern "C" void kernel_launch(void* const* d_in, const int* in_sizes, int n_in,
                              void* d_out, int out_size, void* d_ws, size_t ws_size,
                              hipStream_t stream) {
    const float* in  = (const float*)d_in[0];
    const float* mw1 = (const float*)d_in[1];
    const float* mb1 = (const float*)d_in[2];
    const float* mw2 = (const float*)d_in[3];
    const float* mb2 = (const float*)d_in[4];
    const float* iw1 = (const float*)d_in[5];
    const float* ib1 = (const float*)d_in[6];
    const float* iw2 = (const float*)d_in[7];
    const float* ib2 = (const float*)d_in[8];
    float* out = (float*)d_out;

    char* ws = (char*)d_ws;
    const size_t PART_SZ = (size_t)Bb * WPB_N * Hh * sizeof(float);  // 2 MiB
    float* partials = (float*)(ws);
    float* base     = (float*)(ws + PART_SZ);                        // 8 KiB
    float* xlast    = (float*)(ws + PART_SZ + 8192);                 // 8 MiB
    const size_t need = PART_SZ + 8192 + (size_t)Bb * Nn * sizeof(float);
    const int use_xlast = (ws_size >= need) ? 1 : 0;

    const int nwaves  = (Bb * Nn) / NPW;          // 8192
    const int nblocks = nwaves / (TPB / 64);      // 2048

    hipLaunchKernelGGL(k_mphase, dim3(nblocks), dim3(TPB), 0, stream,
                       in, mw1, mb1, partials, xlast);
    hipLaunchKernelGGL(k_combine, dim3(Bb), dim3(Hh), 0, stream,
                       partials, mw2, mb2, iw1, ib1, base);
    hipLaunchKernelGGL(k_iphase, dim3((Bb * Nn) / TPB), dim3(TPB), 0, stream,
                       use_xlast ? xlast : in, use_xlast ? 1 : Dd,
                       base, iw1, iw2, ib2, out);
}